// Round 5
// baseline (518.373 us; speedup 1.0000x reference)
//
#include <hip/hip_runtime.h>

#define N_NODES  80000
#define N_EDGES  1280000
#define N_GRAPHS 512
#define DIM      64
#define NCLS     10

#define ETILE    8192
#define NTILE    157      // ceil(N_EDGES / ETILE)
#define NCB      157      // ceil(N_NODES / 512) coarse buckets of 512 nodes
#define CBPAD    160

static __device__ __forceinline__ unsigned short f2bf(float f) {
    unsigned u = __float_as_uint(f);
    unsigned r = (u + 0x7FFFu + ((u >> 16) & 1u)) >> 16;   // RNE
    return (unsigned short)r;
}
static __device__ __forceinline__ float bf_lo(unsigned v) { return __uint_as_float(v << 16); }
static __device__ __forceinline__ float bf_hi(unsigned v) { return __uint_as_float(v & 0xFFFF0000u); }

// ---------- Pass A: per-tile histogram over coarse buckets (no global atomics)
__global__ __launch_bounds__(256) void k_hist(const int* __restrict__ ei,
                                              int* __restrict__ hmat) {
    __shared__ int hist[NCB];
    int tile = blockIdx.x, t = threadIdx.x;
    for (int i = t; i < NCB; i += 256) hist[i] = 0;
    __syncthreads();
    int base = tile * ETILE;
    int end = base + ETILE; if (end > N_EDGES) end = N_EDGES;
    for (int i = base + t; i < end; i += 256)
        atomicAdd(&hist[ei[N_EDGES + i] >> 9], 1);
    __syncthreads();
    for (int i = t; i < NCB; i += 256) hmat[tile * CBPAD + i] = hist[i];
}

// ---------- Pass B1: per-bucket scan across tiles -> within-bucket offsets
__global__ __launch_bounds__(256) void k_scanT(const int* __restrict__ hmat,
        int* __restrict__ obase, int* __restrict__ btot) {
    __shared__ int sa[256], sb[256];
    int b = blockIdx.x, t = threadIdx.x;
    int v = (t < NTILE) ? hmat[t * CBPAD + b] : 0;
    sa[t] = v; __syncthreads();
    int* sp = sa; int* dp = sb;
    for (int off = 1; off < 256; off <<= 1) {
        dp[t] = sp[t] + ((t >= off) ? sp[t - off] : 0);
        __syncthreads();
        int* tmp = sp; sp = dp; dp = tmp;
    }
    int incl = sp[t];
    if (t < NTILE) obase[t * CBPAD + b] = incl - v;
    if (t == NTILE - 1) btot[b] = incl;
}

// ---------- Pass B2: scan bucket totals -> bucket bases
__global__ __launch_bounds__(256) void k_scanB(const int* __restrict__ btot,
        int* __restrict__ bucketbase, int* __restrict__ rowptr) {
    __shared__ int sa[256], sb[256];
    int t = threadIdx.x;
    int v = (t < NCB) ? btot[t] : 0;
    sa[t] = v; __syncthreads();
    int* sp = sa; int* dp = sb;
    for (int off = 1; off < 256; off <<= 1) {
        dp[t] = sp[t] + ((t >= off) ? sp[t - off] : 0);
        __syncthreads();
        int* tmp = sp; sp = dp; dp = tmp;
    }
    int incl = sp[t];
    if (t < NCB) bucketbase[t] = incl - v;
    if (t == 0) { bucketbase[NCB] = N_EDGES; rowptr[N_NODES] = N_EDGES; }
}

// ---------- Pass C: scatter into bucket-sorted ebuf (deterministic runs)
__global__ __launch_bounds__(256) void k_scatter(const int* __restrict__ ei,
        const int* __restrict__ obase, const int* __restrict__ bucketbase,
        int* __restrict__ ebuf) {
    __shared__ int cur[NCB];
    int tile = blockIdx.x, t = threadIdx.x;
    for (int i = t; i < NCB; i += 256)
        cur[i] = bucketbase[i] + obase[tile * CBPAD + i];
    __syncthreads();
    int base = tile * ETILE;
    int end = base + ETILE; if (end > N_EDGES) end = N_EDGES;
    for (int i = base + t; i < end; i += 256) {
        int s = ei[i], d = ei[N_EDGES + i];
        int p = atomicAdd(&cur[d >> 9], 1);
        ebuf[p] = s | ((d & 511) << 17);   // src:17 bits, local dst:9 bits
    }
}

// ---------- Pass D: per-bucket node-level CSR, all in LDS
__global__ __launch_bounds__(256) void k_csr(const int* __restrict__ ebuf,
        const int* __restrict__ bucketbase, int* __restrict__ rowptr,
        int* __restrict__ col) {
    __shared__ int cnt[512];
    __shared__ int sa[512], sb[512];
    __shared__ int cur[512];
    int b = blockIdx.x, t = threadIdx.x;
    int s = bucketbase[b], e = bucketbase[b + 1];
    cnt[t] = 0; cnt[t + 256] = 0;
    __syncthreads();
    for (int i = s + t; i < e; i += 256) atomicAdd(&cnt[ebuf[i] >> 17], 1);
    __syncthreads();
    sa[t] = cnt[t]; sa[t + 256] = cnt[t + 256];
    __syncthreads();
    int* sp = sa; int* dp = sb;
    for (int off = 1; off < 512; off <<= 1) {
        int i1 = t + 256;
        int v0 = sp[t]  + ((t  >= off) ? sp[t  - off] : 0);
        int v1 = sp[i1] + ((i1 >= off) ? sp[i1 - off] : 0);
        __syncthreads();
        dp[t] = v0; dp[i1] = v1;
        __syncthreads();
        int* tmp = sp; sp = dp; dp = tmp;
    }
    int node0 = b * 512;
    int base0 = s + sp[t] - cnt[t];
    int base1 = s + sp[t + 256] - cnt[t + 256];
    cur[t] = base0; cur[t + 256] = base1;
    if (node0 + t < N_NODES)       rowptr[node0 + t] = base0;
    if (node0 + t + 256 < N_NODES) rowptr[node0 + t + 256] = base1;
    __syncthreads();
    for (int i = s + t; i < e; i += 256) {
        int pk = ebuf[i];
        int p = atomicAdd(&cur[pk >> 17], 1);
        col[p] = pk & 0x1FFFF;
    }
}

// ---------- weight pre-transpose: wcat[layer][k][n]
__global__ void k_prep(const float* __restrict__ wr1, const float* __restrict__ wo1,
                       const float* __restrict__ wr2, const float* __restrict__ wo2,
                       const float* __restrict__ wr3, const float* __restrict__ wo3,
                       float* __restrict__ wcat) {
    int idx = blockIdx.x * blockDim.x + threadIdx.x;
    if (idx >= 3 * 8192) return;
    int l = idx / 8192, r = idx % 8192, k = r / 64, n = r % 64;
    const float* wr = (l == 0) ? wr1 : (l == 1) ? wr2 : wr3;
    const float* wo = (l == 0) ? wo1 : (l == 1) ? wo2 : wo3;
    wcat[idx] = (k < 64) ? wr[n * 64 + k] : wo[n * 64 + (k - 64)];
}

// ---------- cast fp32 x -> bf16 ----------
__global__ __launch_bounds__(256) void k_cast(const float* __restrict__ x,
                                              unsigned short* __restrict__ xb) {
    int i = blockIdx.x * 256 + threadIdx.x;      // one float4 per thread
    if (i < N_NODES * 16) {
        float4 v = ((const float4*)x)[i];
        ushort4 o;
        o.x = f2bf(v.x); o.y = f2bf(v.y); o.z = f2bf(v.z); o.w = f2bf(v.w);
        ((ushort4*)xb)[i] = o;
    }
}

// ---------- fused layer: gather (bf16) + GEMM (fp32) + bias/relu + bf16 out
// 64 nodes/block; sA is m-major [64][68]; sB k-major [128][64]
__global__ __launch_bounds__(256) void k_layer(const unsigned short* __restrict__ Xbf,
        const int* __restrict__ rowptr, const int* __restrict__ col,
        const float* __restrict__ wcat, const float* __restrict__ bias,
        unsigned short* __restrict__ out, int relu) {
    __shared__ __align__(16) float sA[64 * 68];
    __shared__ __align__(16) float sB[128 * 64];
    __shared__ float sBias[64];
    const unsigned* Xu = (const unsigned*)Xbf;
    int t = threadIdx.x;
    int m0 = blockIdx.x * 64;
    // stage weights + bias
    {
        const float4* wsrc = (const float4*)wcat;
        float4* wdst = (float4*)sB;
#pragma unroll
        for (int r = 0; r < 8; ++r) wdst[r * 256 + t] = wsrc[r * 256 + t];
        if (t < 64) sBias[t] = bias[t];
    }
    // gather phase: wave w, half-group g, channel-pair c
    int w = t >> 6, lane = t & 63, g = lane >> 5, c = lane & 31;
#pragma unroll
    for (int p = 0; p < 8; ++p) {
        int ml = w * 16 + p * 2 + g;
        int node = m0 + ml;
        int start = rowptr[node], end = rowptr[node + 1];
        float alo = 0.f, ahi = 0.f;
        int e = start;
        for (; e + 4 <= end; e += 4) {
            int s0 = col[e], s1 = col[e + 1], s2 = col[e + 2], s3 = col[e + 3];
            unsigned v0 = Xu[(size_t)s0 * 32 + c];
            unsigned v1 = Xu[(size_t)s1 * 32 + c];
            unsigned v2 = Xu[(size_t)s2 * 32 + c];
            unsigned v3 = Xu[(size_t)s3 * 32 + c];
            alo += (bf_lo(v0) + bf_lo(v1)) + (bf_lo(v2) + bf_lo(v3));
            ahi += (bf_hi(v0) + bf_hi(v1)) + (bf_hi(v2) + bf_hi(v3));
        }
        for (; e < end; ++e) {
            unsigned v = Xu[(size_t)col[e] * 32 + c];
            alo += bf_lo(v); ahi += bf_hi(v);
        }
        *(float2*)&sA[ml * 68 + 2 * c] = make_float2(alo, ahi);
    }
    __syncthreads();
    // GEMM pass 0: A = agg, B rows 0..63
    int tn = (t & 15) * 4;
    int tm = (t >> 4) * 4;
    float acc[4][4] = {{0.f}};
#pragma unroll 4
    for (int k4 = 0; k4 < 16; ++k4) {
        float4 b0 = *(const float4*)&sB[(k4 * 4 + 0) * 64 + tn];
        float4 b1 = *(const float4*)&sB[(k4 * 4 + 1) * 64 + tn];
        float4 b2 = *(const float4*)&sB[(k4 * 4 + 2) * 64 + tn];
        float4 b3 = *(const float4*)&sB[(k4 * 4 + 3) * 64 + tn];
#pragma unroll
        for (int i = 0; i < 4; ++i) {
            float4 a = *(const float4*)&sA[(tm + i) * 68 + k4 * 4];
            acc[i][0] += a.x * b0.x + a.y * b1.x + a.z * b2.x + a.w * b3.x;
            acc[i][1] += a.x * b0.y + a.y * b1.y + a.z * b2.y + a.w * b3.y;
            acc[i][2] += a.x * b0.z + a.y * b1.z + a.z * b2.z + a.w * b3.z;
            acc[i][3] += a.x * b0.w + a.y * b1.w + a.z * b2.w + a.w * b3.w;
        }
    }
    __syncthreads();
    // stage root features (bf16 -> fp32) into sA
#pragma unroll
    for (int p = 0; p < 8; ++p) {
        int ml = w * 16 + p * 2 + g;
        unsigned v = Xu[(size_t)(m0 + ml) * 32 + c];
        *(float2*)&sA[ml * 68 + 2 * c] = make_float2(bf_lo(v), bf_hi(v));
    }
    __syncthreads();
    // GEMM pass 1: A = x_root, B rows 64..127
#pragma unroll 4
    for (int k4 = 0; k4 < 16; ++k4) {
        float4 b0 = *(const float4*)&sB[(64 + k4 * 4 + 0) * 64 + tn];
        float4 b1 = *(const float4*)&sB[(64 + k4 * 4 + 1) * 64 + tn];
        float4 b2 = *(const float4*)&sB[(64 + k4 * 4 + 2) * 64 + tn];
        float4 b3 = *(const float4*)&sB[(64 + k4 * 4 + 3) * 64 + tn];
#pragma unroll
        for (int i = 0; i < 4; ++i) {
            float4 a = *(const float4*)&sA[(tm + i) * 68 + k4 * 4];
            acc[i][0] += a.x * b0.x + a.y * b1.x + a.z * b2.x + a.w * b3.x;
            acc[i][1] += a.x * b0.y + a.y * b1.y + a.z * b2.y + a.w * b3.y;
            acc[i][2] += a.x * b0.z + a.y * b1.z + a.z * b2.z + a.w * b3.z;
            acc[i][3] += a.x * b0.w + a.y * b1.w + a.z * b2.w + a.w * b3.w;
        }
    }
    // epilogue: bias, relu, bf16 pack, store ushort4 (8B)
#pragma unroll
    for (int i = 0; i < 4; ++i) {
        float v0 = acc[i][0] + sBias[tn + 0];
        float v1 = acc[i][1] + sBias[tn + 1];
        float v2 = acc[i][2] + sBias[tn + 2];
        float v3 = acc[i][3] + sBias[tn + 3];
        if (relu) {
            v0 = fmaxf(v0, 0.f); v1 = fmaxf(v1, 0.f);
            v2 = fmaxf(v2, 0.f); v3 = fmaxf(v3, 0.f);
        }
        ushort4 o;
        o.x = f2bf(v0); o.y = f2bf(v1); o.z = f2bf(v2); o.w = f2bf(v3);
        *(ushort4*)&out[(size_t)(m0 + tm + i) * 64 + tn] = o;
    }
}

// ---------- mean pool over sorted batch ids (bf16 input) ----------
static __device__ __forceinline__ int lowerb(const int* a, int n, int key) {
    int lo = 0, hi = n;
    while (lo < hi) { int mid = (lo + hi) >> 1; if (a[mid] < key) lo = mid + 1; else hi = mid; }
    return lo;
}

__global__ __launch_bounds__(256) void k_pool(const unsigned short* __restrict__ h,
        const int* __restrict__ batch, float* __restrict__ pooled) {
    __shared__ float sp[8][64];
    int gph = blockIdx.x;
    int t = threadIdx.x, sub = t >> 5, c = t & 31;
    int start = lowerb(batch, N_NODES, gph);
    int end   = lowerb(batch, N_NODES, gph + 1);
    const unsigned* hu = (const unsigned*)h;
    float alo = 0.f, ahi = 0.f;
    for (int i = start + sub; i < end; i += 8) {
        unsigned v = hu[(size_t)i * 32 + c];
        alo += bf_lo(v); ahi += bf_hi(v);
    }
    sp[sub][2 * c] = alo; sp[sub][2 * c + 1] = ahi;
    __syncthreads();
    if (t < 64) {
        float v = 0.f;
#pragma unroll
        for (int s = 0; s < 8; ++s) v += sp[s][t];
        int cnt = end - start;
        v /= (float)((cnt > 0) ? cnt : 1);
        pooled[gph * 64 + t] = v;
    }
}

__global__ void k_head(const float* __restrict__ pooled, const float* __restrict__ wlin,
                       const float* __restrict__ blin, float* __restrict__ out) {
    int g = blockIdx.x, lane = threadIdx.x;
    float p = pooled[g * 64 + lane];
    float myout = 0.f;
    for (int cls = 0; cls < NCLS; ++cls) {
        float v = p * wlin[cls * 64 + lane];
        for (int off = 32; off > 0; off >>= 1) v += __shfl_xor(v, off);
        if (lane == cls) myout = v + blin[cls];
    }
    if (lane < NCLS) out[g * NCLS + lane] = myout;
}

extern "C" void kernel_launch(void* const* d_in, const int* in_sizes, int n_in,
                              void* d_out, int out_size, void* d_ws, size_t ws_size,
                              hipStream_t stream) {
    const float* x     = (const float*)d_in[0];
    const int*   ei    = (const int*)d_in[1];
    const int*   batch = (const int*)d_in[2];
    const float* wr1 = (const float*)d_in[3];
    const float* b1  = (const float*)d_in[4];
    const float* wo1 = (const float*)d_in[5];
    const float* wr2 = (const float*)d_in[6];
    const float* b2  = (const float*)d_in[7];
    const float* wo2 = (const float*)d_in[8];
    const float* wr3 = (const float*)d_in[9];
    const float* b3  = (const float*)d_in[10];
    const float* wo3 = (const float*)d_in[11];
    const float* wlin = (const float*)d_in[12];
    const float* blin = (const float*)d_in[13];
    float* out = (float*)d_out;

    char* p = (char*)d_ws;
    auto alloc = [&](size_t bytes) { char* r = p; p += (bytes + 255) & ~(size_t)255; return r; };
    int*   rowptr  = (int*)alloc((N_NODES + 1) * sizeof(int));
    int*   hmat    = (int*)alloc((size_t)NTILE * CBPAD * sizeof(int));
    int*   obase   = (int*)alloc((size_t)NTILE * CBPAD * sizeof(int));
    int*   btot    = (int*)alloc(CBPAD * sizeof(int));
    int*   bucketbase = (int*)alloc((NCB + 1) * sizeof(int));
    int*   ebuf    = (int*)alloc((size_t)N_EDGES * sizeof(int));
    int*   col     = (int*)alloc((size_t)N_EDGES * sizeof(int));
    float* wcat    = (float*)alloc(3 * 8192 * sizeof(float));
    unsigned short* xbf = (unsigned short*)alloc((size_t)N_NODES * 64 * 2);
    unsigned short* hA  = (unsigned short*)alloc((size_t)N_NODES * 64 * 2);
    unsigned short* hB  = (unsigned short*)alloc((size_t)N_NODES * 64 * 2);
    float* pooled  = (float*)alloc((size_t)N_GRAPHS * 64 * sizeof(float));

    // CSR build: deterministic two-level counting sort, zero global atomics
    k_hist   <<<NTILE, 256, 0, stream>>>(ei, hmat);
    k_scanT  <<<NCB,   256, 0, stream>>>(hmat, obase, btot);
    k_scanB  <<<1,     256, 0, stream>>>(btot, bucketbase, rowptr);
    k_scatter<<<NTILE, 256, 0, stream>>>(ei, obase, bucketbase, ebuf);
    k_csr    <<<NCB,   256, 0, stream>>>(ebuf, bucketbase, rowptr, col);
    k_prep   <<<(3 * 8192 + 255) / 256, 256, 0, stream>>>(wr1, wo1, wr2, wo2, wr3, wo3, wcat);
    k_cast   <<<(N_NODES * 16 + 255) / 256, 256, 0, stream>>>(x, xbf);

    // fused layers (bf16 features, fp32 math)
    k_layer<<<N_NODES / 64, 256, 0, stream>>>(xbf, rowptr, col, wcat,         b1, hA, 1);
    k_layer<<<N_NODES / 64, 256, 0, stream>>>(hA,  rowptr, col, wcat + 8192,  b2, hB, 1);
    k_layer<<<N_NODES / 64, 256, 0, stream>>>(hB,  rowptr, col, wcat + 16384, b3, hA, 0);

    // pool + head
    k_pool<<<N_GRAPHS, 256, 0, stream>>>(hA, batch, pooled);
    k_head<<<N_GRAPHS, 64, 0, stream>>>(pooled, wlin, blin, out);
}

// Round 6
// 449.495 us; speedup vs baseline: 1.1532x; 1.1532x over previous
//
#include <hip/hip_runtime.h>

#define N_NODES  80000
#define N_EDGES  1280000
#define N_GRAPHS 512
#define DIM      64
#define NCLS     10

#define ETILE    8192
#define NTILE    157      // ceil(N_EDGES / ETILE)
#define NCB      157      // ceil(N_NODES / 512) coarse buckets of 512 nodes
#define CBPAD    160

static __device__ __forceinline__ unsigned short f2bf(float f) {
    unsigned u = __float_as_uint(f);
    unsigned r = (u + 0x7FFFu + ((u >> 16) & 1u)) >> 16;   // RNE
    return (unsigned short)r;
}
static __device__ __forceinline__ float bf_lo(unsigned v) { return __uint_as_float(v << 16); }
static __device__ __forceinline__ float bf_hi(unsigned v) { return __uint_as_float(v & 0xFFFF0000u); }

// ---------- Pass A: per-tile histogram over coarse buckets (no global atomics)
__global__ __launch_bounds__(256) void k_hist(const int* __restrict__ ei,
                                              int* __restrict__ hmat) {
    __shared__ int hist[NCB];
    int tile = blockIdx.x, t = threadIdx.x;
    for (int i = t; i < NCB; i += 256) hist[i] = 0;
    __syncthreads();
    int base = tile * ETILE;
    int end = base + ETILE; if (end > N_EDGES) end = N_EDGES;
    for (int i = base + t; i < end; i += 256)
        atomicAdd(&hist[ei[N_EDGES + i] >> 9], 1);
    __syncthreads();
    for (int i = t; i < NCB; i += 256) hmat[tile * CBPAD + i] = hist[i];
}

// ---------- Pass B1: per-bucket scan across tiles -> within-bucket offsets
__global__ __launch_bounds__(256) void k_scanT(const int* __restrict__ hmat,
        int* __restrict__ obase, int* __restrict__ btot) {
    __shared__ int sa[256], sb[256];
    int b = blockIdx.x, t = threadIdx.x;
    int v = (t < NTILE) ? hmat[t * CBPAD + b] : 0;
    sa[t] = v; __syncthreads();
    int* sp = sa; int* dp = sb;
    for (int off = 1; off < 256; off <<= 1) {
        dp[t] = sp[t] + ((t >= off) ? sp[t - off] : 0);
        __syncthreads();
        int* tmp = sp; sp = dp; dp = tmp;
    }
    int incl = sp[t];
    if (t < NTILE) obase[t * CBPAD + b] = incl - v;
    if (t == NTILE - 1) btot[b] = incl;
}

// ---------- Pass B2: scan bucket totals -> bucket bases
__global__ __launch_bounds__(256) void k_scanB(const int* __restrict__ btot,
        int* __restrict__ bucketbase, int* __restrict__ rowptr) {
    __shared__ int sa[256], sb[256];
    int t = threadIdx.x;
    int v = (t < NCB) ? btot[t] : 0;
    sa[t] = v; __syncthreads();
    int* sp = sa; int* dp = sb;
    for (int off = 1; off < 256; off <<= 1) {
        dp[t] = sp[t] + ((t >= off) ? sp[t - off] : 0);
        __syncthreads();
        int* tmp = sp; sp = dp; dp = tmp;
    }
    int incl = sp[t];
    if (t < NCB) bucketbase[t] = incl - v;
    if (t == 0) { bucketbase[NCB] = N_EDGES; rowptr[N_NODES] = N_EDGES; }
}

// ---------- Pass C: scatter into bucket-sorted ebuf (deterministic runs)
__global__ __launch_bounds__(256) void k_scatter(const int* __restrict__ ei,
        const int* __restrict__ obase, const int* __restrict__ bucketbase,
        int* __restrict__ ebuf) {
    __shared__ int cur[NCB];
    int tile = blockIdx.x, t = threadIdx.x;
    for (int i = t; i < NCB; i += 256)
        cur[i] = bucketbase[i] + obase[tile * CBPAD + i];
    __syncthreads();
    int base = tile * ETILE;
    int end = base + ETILE; if (end > N_EDGES) end = N_EDGES;
    for (int i = base + t; i < end; i += 256) {
        int s = ei[i], d = ei[N_EDGES + i];
        int p = atomicAdd(&cur[d >> 9], 1);
        ebuf[p] = s | ((d & 511) << 17);   // src:17 bits, local dst:9 bits
    }
}

// ---------- Pass D: per-bucket node-level CSR, all in LDS
__global__ __launch_bounds__(256) void k_csr(const int* __restrict__ ebuf,
        const int* __restrict__ bucketbase, int* __restrict__ rowptr,
        int* __restrict__ col) {
    __shared__ int cnt[512];
    __shared__ int sa[512], sb[512];
    __shared__ int cur[512];
    int b = blockIdx.x, t = threadIdx.x;
    int s = bucketbase[b], e = bucketbase[b + 1];
    cnt[t] = 0; cnt[t + 256] = 0;
    __syncthreads();
    for (int i = s + t; i < e; i += 256) atomicAdd(&cnt[ebuf[i] >> 17], 1);
    __syncthreads();
    sa[t] = cnt[t]; sa[t + 256] = cnt[t + 256];
    __syncthreads();
    int* sp = sa; int* dp = sb;
    for (int off = 1; off < 512; off <<= 1) {
        int i1 = t + 256;
        int v0 = sp[t]  + ((t  >= off) ? sp[t  - off] : 0);
        int v1 = sp[i1] + ((i1 >= off) ? sp[i1 - off] : 0);
        __syncthreads();
        dp[t] = v0; dp[i1] = v1;
        __syncthreads();
        int* tmp = sp; sp = dp; dp = tmp;
    }
    int node0 = b * 512;
    int base0 = s + sp[t] - cnt[t];
    int base1 = s + sp[t + 256] - cnt[t + 256];
    cur[t] = base0; cur[t + 256] = base1;
    if (node0 + t < N_NODES)       rowptr[node0 + t] = base0;
    if (node0 + t + 256 < N_NODES) rowptr[node0 + t + 256] = base1;
    __syncthreads();
    for (int i = s + t; i < e; i += 256) {
        int pk = ebuf[i];
        int p = atomicAdd(&cur[pk >> 17], 1);
        col[p] = pk & 0x1FFFF;
    }
}

// ---------- weight pre-transpose: wcat[layer][k][n]
__global__ void k_prep(const float* __restrict__ wr1, const float* __restrict__ wo1,
                       const float* __restrict__ wr2, const float* __restrict__ wo2,
                       const float* __restrict__ wr3, const float* __restrict__ wo3,
                       float* __restrict__ wcat) {
    int idx = blockIdx.x * blockDim.x + threadIdx.x;
    if (idx >= 3 * 8192) return;
    int l = idx / 8192, r = idx % 8192, k = r / 64, n = r % 64;
    const float* wr = (l == 0) ? wr1 : (l == 1) ? wr2 : wr3;
    const float* wo = (l == 0) ? wo1 : (l == 1) ? wo2 : wo3;
    wcat[idx] = (k < 64) ? wr[n * 64 + k] : wo[n * 64 + (k - 64)];
}

// ---------- cast fp32 x -> bf16 ----------
__global__ __launch_bounds__(256) void k_cast(const float* __restrict__ x,
                                              unsigned short* __restrict__ xb) {
    int i = blockIdx.x * 256 + threadIdx.x;      // one float4 per thread
    if (i < N_NODES * 16) {
        float4 v = ((const float4*)x)[i];
        ushort4 o;
        o.x = f2bf(v.x); o.y = f2bf(v.y); o.z = f2bf(v.z); o.w = f2bf(v.w);
        ((ushort4*)xb)[i] = o;
    }
}

// ---------- aggregation over bf16 rows: 2 nodes/wave, lane=dword, unroll 8
__global__ __launch_bounds__(256) void k_gather_bf(const unsigned short* __restrict__ Xbf,
        const int* __restrict__ rowptr, const int* __restrict__ col,
        unsigned short* __restrict__ agg) {
    const unsigned* Xu = (const unsigned*)Xbf;
    int t = threadIdx.x, w = t >> 6, lane = t & 63;
    int g = lane >> 5, c = lane & 31;
    int node = blockIdx.x * 8 + w * 2 + g;
    int start = rowptr[node], end = rowptr[node + 1];
    float alo = 0.f, ahi = 0.f;
    int e = start;
    for (; e + 8 <= end; e += 8) {
        int s0 = col[e],     s1 = col[e + 1], s2 = col[e + 2], s3 = col[e + 3];
        int s4 = col[e + 4], s5 = col[e + 5], s6 = col[e + 6], s7 = col[e + 7];
        unsigned v0 = Xu[(size_t)s0 * 32 + c];
        unsigned v1 = Xu[(size_t)s1 * 32 + c];
        unsigned v2 = Xu[(size_t)s2 * 32 + c];
        unsigned v3 = Xu[(size_t)s3 * 32 + c];
        unsigned v4 = Xu[(size_t)s4 * 32 + c];
        unsigned v5 = Xu[(size_t)s5 * 32 + c];
        unsigned v6 = Xu[(size_t)s6 * 32 + c];
        unsigned v7 = Xu[(size_t)s7 * 32 + c];
        alo += ((bf_lo(v0) + bf_lo(v1)) + (bf_lo(v2) + bf_lo(v3)))
             + ((bf_lo(v4) + bf_lo(v5)) + (bf_lo(v6) + bf_lo(v7)));
        ahi += ((bf_hi(v0) + bf_hi(v1)) + (bf_hi(v2) + bf_hi(v3)))
             + ((bf_hi(v4) + bf_hi(v5)) + (bf_hi(v6) + bf_hi(v7)));
    }
    for (; e < end; ++e) {
        unsigned v = Xu[(size_t)col[e] * 32 + c];
        alo += bf_lo(v); ahi += bf_hi(v);
    }
    unsigned o = (unsigned)f2bf(alo) | ((unsigned)f2bf(ahi) << 16);
    ((unsigned*)agg)[(size_t)node * 32 + c] = o;
}

// ---------- GEMM: out = act(AGG@Wrel^T + X@Wroot^T + b), bf16 in/out
// sA bf16 rows padded to 34 dwords (conflict-free); sB fp32 k-major
__global__ __launch_bounds__(256) void k_linear_bf(const unsigned short* __restrict__ aggb,
        const unsigned short* __restrict__ xb, const float* __restrict__ wcat,
        const float* __restrict__ bias, unsigned short* __restrict__ out, int relu) {
    __shared__ __align__(16) unsigned sA[64 * 34];    // 8704 B
    __shared__ __align__(16) float sB[128 * 64];      // 32 KB
    __shared__ float sBias[64];
    int t = threadIdx.x;
    int m0 = blockIdx.x * 64;
    {
        const float4* wsrc = (const float4*)wcat;
        float4* wdst = (float4*)sB;
#pragma unroll
        for (int r = 0; r < 8; ++r) wdst[r * 256 + t] = wsrc[r * 256 + t];
        if (t < 64) sBias[t] = bias[t];
    }
    float acc[4][4] = {{0.f}};
    int tn = (t & 15) * 4;
    int tm = (t >> 4) * 4;
    const unsigned* srcs[2] = {(const unsigned*)aggb, (const unsigned*)xb};
    for (int pass = 0; pass < 2; ++pass) {
        const unsigned* S = srcs[pass];
        __syncthreads();   // pass0: sB ready; pass1: sA readers done
        // stage 64 bf16 rows (32 dwords each) into padded sA
#pragma unroll
        for (int r8 = 0; r8 < 8; ++r8) {
            int i = r8 * 256 + t;
            int r = i >> 5, cdw = i & 31;
            sA[r * 34 + cdw] = S[(size_t)(m0 + r) * 32 + cdw];
        }
        __syncthreads();
        const float* Bp = sB + pass * 4096;
#pragma unroll
        for (int k4 = 0; k4 < 16; ++k4) {
            float4 b0 = *(const float4*)&Bp[(k4 * 4 + 0) * 64 + tn];
            float4 b1 = *(const float4*)&Bp[(k4 * 4 + 1) * 64 + tn];
            float4 b2 = *(const float4*)&Bp[(k4 * 4 + 2) * 64 + tn];
            float4 b3 = *(const float4*)&Bp[(k4 * 4 + 3) * 64 + tn];
#pragma unroll
            for (int i = 0; i < 4; ++i) {
                uint2 ap = *(const uint2*)&sA[(tm + i) * 34 + k4 * 2];
                float a0 = bf_lo(ap.x), a1 = bf_hi(ap.x);
                float a2 = bf_lo(ap.y), a3 = bf_hi(ap.y);
                acc[i][0] += a0 * b0.x + a1 * b1.x + a2 * b2.x + a3 * b3.x;
                acc[i][1] += a0 * b0.y + a1 * b1.y + a2 * b2.y + a3 * b3.y;
                acc[i][2] += a0 * b0.z + a1 * b1.z + a2 * b2.z + a3 * b3.z;
                acc[i][3] += a0 * b0.w + a1 * b1.w + a2 * b2.w + a3 * b3.w;
            }
        }
    }
#pragma unroll
    for (int i = 0; i < 4; ++i) {
        float v0 = acc[i][0] + sBias[tn + 0];
        float v1 = acc[i][1] + sBias[tn + 1];
        float v2 = acc[i][2] + sBias[tn + 2];
        float v3 = acc[i][3] + sBias[tn + 3];
        if (relu) {
            v0 = fmaxf(v0, 0.f); v1 = fmaxf(v1, 0.f);
            v2 = fmaxf(v2, 0.f); v3 = fmaxf(v3, 0.f);
        }
        ushort4 o;
        o.x = f2bf(v0); o.y = f2bf(v1); o.z = f2bf(v2); o.w = f2bf(v3);
        *(ushort4*)&out[(size_t)(m0 + tm + i) * 64 + tn] = o;
    }
}

// ---------- mean pool over sorted batch ids (bf16 input) ----------
static __device__ __forceinline__ int lowerb(const int* a, int n, int key) {
    int lo = 0, hi = n;
    while (lo < hi) { int mid = (lo + hi) >> 1; if (a[mid] < key) lo = mid + 1; else hi = mid; }
    return lo;
}

__global__ __launch_bounds__(256) void k_pool(const unsigned short* __restrict__ h,
        const int* __restrict__ batch, float* __restrict__ pooled) {
    __shared__ float sp[8][64];
    int gph = blockIdx.x;
    int t = threadIdx.x, sub = t >> 5, c = t & 31;
    int start = lowerb(batch, N_NODES, gph);
    int end   = lowerb(batch, N_NODES, gph + 1);
    const unsigned* hu = (const unsigned*)h;
    float alo = 0.f, ahi = 0.f;
    for (int i = start + sub; i < end; i += 8) {
        unsigned v = hu[(size_t)i * 32 + c];
        alo += bf_lo(v); ahi += bf_hi(v);
    }
    sp[sub][2 * c] = alo; sp[sub][2 * c + 1] = ahi;
    __syncthreads();
    if (t < 64) {
        float v = 0.f;
#pragma unroll
        for (int s = 0; s < 8; ++s) v += sp[s][t];
        int cnt = end - start;
        v /= (float)((cnt > 0) ? cnt : 1);
        pooled[gph * 64 + t] = v;
    }
}

__global__ void k_head(const float* __restrict__ pooled, const float* __restrict__ wlin,
                       const float* __restrict__ blin, float* __restrict__ out) {
    int g = blockIdx.x, lane = threadIdx.x;
    float p = pooled[g * 64 + lane];
    float myout = 0.f;
    for (int cls = 0; cls < NCLS; ++cls) {
        float v = p * wlin[cls * 64 + lane];
        for (int off = 32; off > 0; off >>= 1) v += __shfl_xor(v, off);
        if (lane == cls) myout = v + blin[cls];
    }
    if (lane < NCLS) out[g * NCLS + lane] = myout;
}

extern "C" void kernel_launch(void* const* d_in, const int* in_sizes, int n_in,
                              void* d_out, int out_size, void* d_ws, size_t ws_size,
                              hipStream_t stream) {
    const float* x     = (const float*)d_in[0];
    const int*   ei    = (const int*)d_in[1];
    const int*   batch = (const int*)d_in[2];
    const float* wr1 = (const float*)d_in[3];
    const float* b1  = (const float*)d_in[4];
    const float* wo1 = (const float*)d_in[5];
    const float* wr2 = (const float*)d_in[6];
    const float* b2  = (const float*)d_in[7];
    const float* wo2 = (const float*)d_in[8];
    const float* wr3 = (const float*)d_in[9];
    const float* b3  = (const float*)d_in[10];
    const float* wo3 = (const float*)d_in[11];
    const float* wlin = (const float*)d_in[12];
    const float* blin = (const float*)d_in[13];
    float* out = (float*)d_out;

    char* p = (char*)d_ws;
    auto alloc = [&](size_t bytes) { char* r = p; p += (bytes + 255) & ~(size_t)255; return r; };
    int*   rowptr  = (int*)alloc((N_NODES + 1) * sizeof(int));
    int*   hmat    = (int*)alloc((size_t)NTILE * CBPAD * sizeof(int));
    int*   obase   = (int*)alloc((size_t)NTILE * CBPAD * sizeof(int));
    int*   btot    = (int*)alloc(CBPAD * sizeof(int));
    int*   bucketbase = (int*)alloc((NCB + 1) * sizeof(int));
    int*   ebuf    = (int*)alloc((size_t)N_EDGES * sizeof(int));
    int*   col     = (int*)alloc((size_t)N_EDGES * sizeof(int));
    float* wcat    = (float*)alloc(3 * 8192 * sizeof(float));
    unsigned short* xbf = (unsigned short*)alloc((size_t)N_NODES * 64 * 2);
    unsigned short* agg = (unsigned short*)alloc((size_t)N_NODES * 64 * 2);
    unsigned short* hA  = (unsigned short*)alloc((size_t)N_NODES * 64 * 2);
    unsigned short* hB  = (unsigned short*)alloc((size_t)N_NODES * 64 * 2);
    float* pooled  = (float*)alloc((size_t)N_GRAPHS * 64 * sizeof(float));

    // CSR build: deterministic two-level counting sort, zero global atomics
    k_hist   <<<NTILE, 256, 0, stream>>>(ei, hmat);
    k_scanT  <<<NCB,   256, 0, stream>>>(hmat, obase, btot);
    k_scanB  <<<1,     256, 0, stream>>>(btot, bucketbase, rowptr);
    k_scatter<<<NTILE, 256, 0, stream>>>(ei, obase, bucketbase, ebuf);
    k_csr    <<<NCB,   256, 0, stream>>>(ebuf, bucketbase, rowptr, col);
    k_prep   <<<(3 * 8192 + 255) / 256, 256, 0, stream>>>(wr1, wo1, wr2, wo2, wr3, wo3, wcat);
    k_cast   <<<(N_NODES * 16 + 255) / 256, 256, 0, stream>>>(x, xbf);

    // layer 1
    k_gather_bf<<<N_NODES / 8, 256, 0, stream>>>(xbf, rowptr, col, agg);
    k_linear_bf<<<N_NODES / 64, 256, 0, stream>>>(agg, xbf, wcat,         b1, hA, 1);
    // layer 2
    k_gather_bf<<<N_NODES / 8, 256, 0, stream>>>(hA, rowptr, col, agg);
    k_linear_bf<<<N_NODES / 64, 256, 0, stream>>>(agg, hA, wcat + 8192,  b2, hB, 1);
    // layer 3
    k_gather_bf<<<N_NODES / 8, 256, 0, stream>>>(hB, rowptr, col, agg);
    k_linear_bf<<<N_NODES / 64, 256, 0, stream>>>(agg, hB, wcat + 16384, b3, hA, 0);

    // pool + head
    k_pool<<<N_GRAPHS, 256, 0, stream>>>(hA, batch, pooled);
    k_head<<<N_GRAPHS, 64, 0, stream>>>(pooled, wlin, blin, out);
}

// Round 7
// 348.762 us; speedup vs baseline: 1.4863x; 1.2888x over previous
//
#include <hip/hip_runtime.h>

#define N_NODES  80000
#define N_EDGES  1280000
#define N_GRAPHS 512
#define DIM      64
#define NCLS     10

#define ETILE    8192
#define NTILE    157      // ceil(N_EDGES / ETILE)
#define NCB      157      // ceil(N_NODES / 512) coarse buckets of 512 nodes
#define CBPAD    160

static __device__ __forceinline__ unsigned short f2bf(float f) {
    unsigned u = __float_as_uint(f);
    unsigned r = (u + 0x7FFFu + ((u >> 16) & 1u)) >> 16;   // RNE
    return (unsigned short)r;
}
static __device__ __forceinline__ float bf_lo(unsigned v) { return __uint_as_float(v << 16); }
static __device__ __forceinline__ float bf_hi(unsigned v) { return __uint_as_float(v & 0xFFFF0000u); }

// ---------- Pass A: per-tile histogram over coarse buckets (no global atomics)
__global__ __launch_bounds__(256) void k_hist(const int* __restrict__ ei,
                                              int* __restrict__ hmat) {
    __shared__ int hist[NCB];
    int tile = blockIdx.x, t = threadIdx.x;
    for (int i = t; i < NCB; i += 256) hist[i] = 0;
    __syncthreads();
    int base = tile * ETILE;
    int end = base + ETILE; if (end > N_EDGES) end = N_EDGES;
    for (int i = base + t; i < end; i += 256)
        atomicAdd(&hist[ei[N_EDGES + i] >> 9], 1);
    __syncthreads();
    for (int i = t; i < NCB; i += 256) hmat[tile * CBPAD + i] = hist[i];
}

// ---------- Pass B1: per-bucket scan across tiles -> within-bucket offsets
__global__ __launch_bounds__(256) void k_scanT(const int* __restrict__ hmat,
        int* __restrict__ obase, int* __restrict__ btot) {
    __shared__ int sa[256], sb[256];
    int b = blockIdx.x, t = threadIdx.x;
    int v = (t < NTILE) ? hmat[t * CBPAD + b] : 0;
    sa[t] = v; __syncthreads();
    int* sp = sa; int* dp = sb;
    for (int off = 1; off < 256; off <<= 1) {
        dp[t] = sp[t] + ((t >= off) ? sp[t - off] : 0);
        __syncthreads();
        int* tmp = sp; sp = dp; dp = tmp;
    }
    int incl = sp[t];
    if (t < NTILE) obase[t * CBPAD + b] = incl - v;
    if (t == NTILE - 1) btot[b] = incl;
}

// ---------- Pass B2: scan bucket totals -> bucket bases
__global__ __launch_bounds__(256) void k_scanB(const int* __restrict__ btot,
        int* __restrict__ bucketbase, int* __restrict__ rowptr) {
    __shared__ int sa[256], sb[256];
    int t = threadIdx.x;
    int v = (t < NCB) ? btot[t] : 0;
    sa[t] = v; __syncthreads();
    int* sp = sa; int* dp = sb;
    for (int off = 1; off < 256; off <<= 1) {
        dp[t] = sp[t] + ((t >= off) ? sp[t - off] : 0);
        __syncthreads();
        int* tmp = sp; sp = dp; dp = tmp;
    }
    int incl = sp[t];
    if (t < NCB) bucketbase[t] = incl - v;
    if (t == 0) { bucketbase[NCB] = N_EDGES; rowptr[N_NODES] = N_EDGES; }
}

// ---------- Pass C: scatter into bucket-sorted ebuf (deterministic runs)
__global__ __launch_bounds__(256) void k_scatter(const int* __restrict__ ei,
        const int* __restrict__ obase, const int* __restrict__ bucketbase,
        int* __restrict__ ebuf) {
    __shared__ int cur[NCB];
    int tile = blockIdx.x, t = threadIdx.x;
    for (int i = t; i < NCB; i += 256)
        cur[i] = bucketbase[i] + obase[tile * CBPAD + i];
    __syncthreads();
    int base = tile * ETILE;
    int end = base + ETILE; if (end > N_EDGES) end = N_EDGES;
    for (int i = base + t; i < end; i += 256) {
        int s = ei[i], d = ei[N_EDGES + i];
        int p = atomicAdd(&cur[d >> 9], 1);
        ebuf[p] = s | ((d & 511) << 17);   // src:17 bits, local dst:9 bits
    }
}

// ---------- Pass D: per-bucket node-level CSR, all in LDS
__global__ __launch_bounds__(256) void k_csr(const int* __restrict__ ebuf,
        const int* __restrict__ bucketbase, int* __restrict__ rowptr,
        int* __restrict__ col) {
    __shared__ int cnt[512];
    __shared__ int sa[512], sb[512];
    __shared__ int cur[512];
    int b = blockIdx.x, t = threadIdx.x;
    int s = bucketbase[b], e = bucketbase[b + 1];
    cnt[t] = 0; cnt[t + 256] = 0;
    __syncthreads();
    for (int i = s + t; i < e; i += 256) atomicAdd(&cnt[ebuf[i] >> 17], 1);
    __syncthreads();
    sa[t] = cnt[t]; sa[t + 256] = cnt[t + 256];
    __syncthreads();
    int* sp = sa; int* dp = sb;
    for (int off = 1; off < 512; off <<= 1) {
        int i1 = t + 256;
        int v0 = sp[t]  + ((t  >= off) ? sp[t  - off] : 0);
        int v1 = sp[i1] + ((i1 >= off) ? sp[i1 - off] : 0);
        __syncthreads();
        dp[t] = v0; dp[i1] = v1;
        __syncthreads();
        int* tmp = sp; sp = dp; dp = tmp;
    }
    int node0 = b * 512;
    int base0 = s + sp[t] - cnt[t];
    int base1 = s + sp[t + 256] - cnt[t + 256];
    cur[t] = base0; cur[t + 256] = base1;
    if (node0 + t < N_NODES)       rowptr[node0 + t] = base0;
    if (node0 + t + 256 < N_NODES) rowptr[node0 + t + 256] = base1;
    __syncthreads();
    for (int i = s + t; i < e; i += 256) {
        int pk = ebuf[i];
        int p = atomicAdd(&cur[pk >> 17], 1);
        col[p] = pk & 0x1FFFF;
    }
}

// ---------- weight pre-transpose: wcat[layer][k][n]
__global__ void k_prep(const float* __restrict__ wr1, const float* __restrict__ wo1,
                       const float* __restrict__ wr2, const float* __restrict__ wo2,
                       const float* __restrict__ wr3, const float* __restrict__ wo3,
                       float* __restrict__ wcat) {
    int idx = blockIdx.x * blockDim.x + threadIdx.x;
    if (idx >= 3 * 8192) return;
    int l = idx / 8192, r = idx % 8192, k = r / 64, n = r % 64;
    const float* wr = (l == 0) ? wr1 : (l == 1) ? wr2 : wr3;
    const float* wo = (l == 0) ? wo1 : (l == 1) ? wo2 : wo3;
    wcat[idx] = (k < 64) ? wr[n * 64 + k] : wo[n * 64 + (k - 64)];
}

// ---------- cast fp32 x -> bf16 ----------
__global__ __launch_bounds__(256) void k_cast(const float* __restrict__ x,
                                              unsigned short* __restrict__ xb) {
    int i = blockIdx.x * 256 + threadIdx.x;      // one float4 per thread
    if (i < N_NODES * 16) {
        float4 v = ((const float4*)x)[i];
        ushort4 o;
        o.x = f2bf(v.x); o.y = f2bf(v.y); o.z = f2bf(v.z); o.w = f2bf(v.w);
        ((ushort4*)xb)[i] = o;
    }
}

// ---------- aggregation over bf16 rows: 2 nodes/wave, lane=dword, unroll 8
__global__ __launch_bounds__(256) void k_gather_bf(const unsigned short* __restrict__ Xbf,
        const int* __restrict__ rowptr, const int* __restrict__ col,
        unsigned short* __restrict__ agg) {
    const unsigned* Xu = (const unsigned*)Xbf;
    int t = threadIdx.x, w = t >> 6, lane = t & 63;
    int g = lane >> 5, c = lane & 31;
    int node = blockIdx.x * 8 + w * 2 + g;
    int start = rowptr[node], end = rowptr[node + 1];
    float alo = 0.f, ahi = 0.f;
    int e = start;
    for (; e + 8 <= end; e += 8) {
        int s0 = col[e],     s1 = col[e + 1], s2 = col[e + 2], s3 = col[e + 3];
        int s4 = col[e + 4], s5 = col[e + 5], s6 = col[e + 6], s7 = col[e + 7];
        unsigned v0 = Xu[(size_t)s0 * 32 + c];
        unsigned v1 = Xu[(size_t)s1 * 32 + c];
        unsigned v2 = Xu[(size_t)s2 * 32 + c];
        unsigned v3 = Xu[(size_t)s3 * 32 + c];
        unsigned v4 = Xu[(size_t)s4 * 32 + c];
        unsigned v5 = Xu[(size_t)s5 * 32 + c];
        unsigned v6 = Xu[(size_t)s6 * 32 + c];
        unsigned v7 = Xu[(size_t)s7 * 32 + c];
        alo += ((bf_lo(v0) + bf_lo(v1)) + (bf_lo(v2) + bf_lo(v3)))
             + ((bf_lo(v4) + bf_lo(v5)) + (bf_lo(v6) + bf_lo(v7)));
        ahi += ((bf_hi(v0) + bf_hi(v1)) + (bf_hi(v2) + bf_hi(v3)))
             + ((bf_hi(v4) + bf_hi(v5)) + (bf_hi(v6) + bf_hi(v7)));
    }
    for (; e < end; ++e) {
        unsigned v = Xu[(size_t)col[e] * 32 + c];
        alo += bf_lo(v); ahi += bf_hi(v);
    }
    unsigned o = (unsigned)f2bf(alo) | ((unsigned)f2bf(ahi) << 16);
    ((unsigned*)agg)[(size_t)node * 32 + c] = o;
}

// ---------- GEMM: out = act(AGG@Wrel^T + X@Wroot^T + b), bf16 in/out
// sA fp32 m-major padded 68 (conversion at staging); sB fp32 k-major
__global__ __launch_bounds__(256) void k_linear_bf(const unsigned short* __restrict__ aggb,
        const unsigned short* __restrict__ xb, const float* __restrict__ wcat,
        const float* __restrict__ bias, unsigned short* __restrict__ out, int relu) {
    __shared__ __align__(16) float sA[64 * 68];       // 17.4 KB
    __shared__ __align__(16) float sB[128 * 64];      // 32 KB
    __shared__ float sBias[64];
    int t = threadIdx.x;
    int m0 = blockIdx.x * 64;
    {
        const float4* wsrc = (const float4*)wcat;
        float4* wdst = (float4*)sB;
#pragma unroll
        for (int r = 0; r < 8; ++r) wdst[r * 256 + t] = wsrc[r * 256 + t];
        if (t < 64) sBias[t] = bias[t];
    }
    float acc[4][4] = {{0.f}};
    int tn = (t & 15) * 4;
    int tm = (t >> 4) * 4;
    const unsigned* srcs[2] = {(const unsigned*)aggb, (const unsigned*)xb};
    for (int pass = 0; pass < 2; ++pass) {
        const unsigned* S = srcs[pass];
        __syncthreads();   // pass0: sB ready; pass1: sA readers done
        // stage 64 rows: bf16 pair -> 2 fp32, float2 write (2-way = free)
#pragma unroll
        for (int r8 = 0; r8 < 8; ++r8) {
            int i = r8 * 256 + t;
            int r = i >> 5, cdw = i & 31;
            unsigned v = S[(size_t)(m0 + r) * 32 + cdw];
            *(float2*)&sA[r * 68 + 2 * cdw] = make_float2(bf_lo(v), bf_hi(v));
        }
        __syncthreads();
        const float* Bp = sB + pass * 4096;
#pragma unroll 2
        for (int k4 = 0; k4 < 16; ++k4) {
            float4 b0 = *(const float4*)&Bp[(k4 * 4 + 0) * 64 + tn];
            float4 b1 = *(const float4*)&Bp[(k4 * 4 + 1) * 64 + tn];
            float4 b2 = *(const float4*)&Bp[(k4 * 4 + 2) * 64 + tn];
            float4 b3 = *(const float4*)&Bp[(k4 * 4 + 3) * 64 + tn];
#pragma unroll
            for (int i = 0; i < 4; ++i) {
                float4 a = *(const float4*)&sA[(tm + i) * 68 + k4 * 4];
                acc[i][0] += a.x * b0.x + a.y * b1.x + a.z * b2.x + a.w * b3.x;
                acc[i][1] += a.x * b0.y + a.y * b1.y + a.z * b2.y + a.w * b3.y;
                acc[i][2] += a.x * b0.z + a.y * b1.z + a.z * b2.z + a.w * b3.z;
                acc[i][3] += a.x * b0.w + a.y * b1.w + a.z * b2.w + a.w * b3.w;
            }
        }
    }
#pragma unroll
    for (int i = 0; i < 4; ++i) {
        float v0 = acc[i][0] + sBias[tn + 0];
        float v1 = acc[i][1] + sBias[tn + 1];
        float v2 = acc[i][2] + sBias[tn + 2];
        float v3 = acc[i][3] + sBias[tn + 3];
        if (relu) {
            v0 = fmaxf(v0, 0.f); v1 = fmaxf(v1, 0.f);
            v2 = fmaxf(v2, 0.f); v3 = fmaxf(v3, 0.f);
        }
        ushort4 o;
        o.x = f2bf(v0); o.y = f2bf(v1); o.z = f2bf(v2); o.w = f2bf(v3);
        *(ushort4*)&out[(size_t)(m0 + tm + i) * 64 + tn] = o;
    }
}

// ---------- mean pool over sorted batch ids (bf16 input) ----------
static __device__ __forceinline__ int lowerb(const int* a, int n, int key) {
    int lo = 0, hi = n;
    while (lo < hi) { int mid = (lo + hi) >> 1; if (a[mid] < key) lo = mid + 1; else hi = mid; }
    return lo;
}

__global__ __launch_bounds__(256) void k_pool(const unsigned short* __restrict__ h,
        const int* __restrict__ batch, float* __restrict__ pooled) {
    __shared__ float sp[8][64];
    int gph = blockIdx.x;
    int t = threadIdx.x, sub = t >> 5, c = t & 31;
    int start = lowerb(batch, N_NODES, gph);
    int end   = lowerb(batch, N_NODES, gph + 1);
    const unsigned* hu = (const unsigned*)h;
    float alo = 0.f, ahi = 0.f;
    for (int i = start + sub; i < end; i += 8) {
        unsigned v = hu[(size_t)i * 32 + c];
        alo += bf_lo(v); ahi += bf_hi(v);
    }
    sp[sub][2 * c] = alo; sp[sub][2 * c + 1] = ahi;
    __syncthreads();
    if (t < 64) {
        float v = 0.f;
#pragma unroll
        for (int s = 0; s < 8; ++s) v += sp[s][t];
        int cnt = end - start;
        v /= (float)((cnt > 0) ? cnt : 1);
        pooled[gph * 64 + t] = v;
    }
}

__global__ void k_head(const float* __restrict__ pooled, const float* __restrict__ wlin,
                       const float* __restrict__ blin, float* __restrict__ out) {
    int g = blockIdx.x, lane = threadIdx.x;
    float p = pooled[g * 64 + lane];
    float myout = 0.f;
    for (int cls = 0; cls < NCLS; ++cls) {
        float v = p * wlin[cls * 64 + lane];
        for (int off = 32; off > 0; off >>= 1) v += __shfl_xor(v, off);
        if (lane == cls) myout = v + blin[cls];
    }
    if (lane < NCLS) out[g * NCLS + lane] = myout;
}

extern "C" void kernel_launch(void* const* d_in, const int* in_sizes, int n_in,
                              void* d_out, int out_size, void* d_ws, size_t ws_size,
                              hipStream_t stream) {
    const float* x     = (const float*)d_in[0];
    const int*   ei    = (const int*)d_in[1];
    const int*   batch = (const int*)d_in[2];
    const float* wr1 = (const float*)d_in[3];
    const float* b1  = (const float*)d_in[4];
    const float* wo1 = (const float*)d_in[5];
    const float* wr2 = (const float*)d_in[6];
    const float* b2  = (const float*)d_in[7];
    const float* wo2 = (const float*)d_in[8];
    const float* wr3 = (const float*)d_in[9];
    const float* b3  = (const float*)d_in[10];
    const float* wo3 = (const float*)d_in[11];
    const float* wlin = (const float*)d_in[12];
    const float* blin = (const float*)d_in[13];
    float* out = (float*)d_out;

    char* p = (char*)d_ws;
    auto alloc = [&](size_t bytes) { char* r = p; p += (bytes + 255) & ~(size_t)255; return r; };
    int*   rowptr  = (int*)alloc((N_NODES + 1) * sizeof(int));
    int*   hmat    = (int*)alloc((size_t)NTILE * CBPAD * sizeof(int));
    int*   obase   = (int*)alloc((size_t)NTILE * CBPAD * sizeof(int));
    int*   btot    = (int*)alloc(CBPAD * sizeof(int));
    int*   bucketbase = (int*)alloc((NCB + 1) * sizeof(int));
    int*   ebuf    = (int*)alloc((size_t)N_EDGES * sizeof(int));
    int*   col     = (int*)alloc((size_t)N_EDGES * sizeof(int));
    float* wcat    = (float*)alloc(3 * 8192 * sizeof(float));
    unsigned short* xbf = (unsigned short*)alloc((size_t)N_NODES * 64 * 2);
    unsigned short* agg = (unsigned short*)alloc((size_t)N_NODES * 64 * 2);
    unsigned short* hA  = (unsigned short*)alloc((size_t)N_NODES * 64 * 2);
    unsigned short* hB  = (unsigned short*)alloc((size_t)N_NODES * 64 * 2);
    float* pooled  = (float*)alloc((size_t)N_GRAPHS * 64 * sizeof(float));

    // CSR build: deterministic two-level counting sort, zero global atomics
    k_hist   <<<NTILE, 256, 0, stream>>>(ei, hmat);
    k_scanT  <<<NCB,   256, 0, stream>>>(hmat, obase, btot);
    k_scanB  <<<1,     256, 0, stream>>>(btot, bucketbase, rowptr);
    k_scatter<<<NTILE, 256, 0, stream>>>(ei, obase, bucketbase, ebuf);
    k_csr    <<<NCB,   256, 0, stream>>>(ebuf, bucketbase, rowptr, col);
    k_prep   <<<(3 * 8192 + 255) / 256, 256, 0, stream>>>(wr1, wo1, wr2, wo2, wr3, wo3, wcat);
    k_cast   <<<(N_NODES * 16 + 255) / 256, 256, 0, stream>>>(x, xbf);

    // layer 1
    k_gather_bf<<<N_NODES / 8, 256, 0, stream>>>(xbf, rowptr, col, agg);
    k_linear_bf<<<N_NODES / 64, 256, 0, stream>>>(agg, xbf, wcat,         b1, hA, 1);
    // layer 2
    k_gather_bf<<<N_NODES / 8, 256, 0, stream>>>(hA, rowptr, col, agg);
    k_linear_bf<<<N_NODES / 64, 256, 0, stream>>>(agg, hA, wcat + 8192,  b2, hB, 1);
    // layer 3
    k_gather_bf<<<N_NODES / 8, 256, 0, stream>>>(hB, rowptr, col, agg);
    k_linear_bf<<<N_NODES / 64, 256, 0, stream>>>(agg, hB, wcat + 16384, b3, hA, 0);

    // pool + head
    k_pool<<<N_GRAPHS, 256, 0, stream>>>(hA, batch, pooled);
    k_head<<<N_GRAPHS, 64, 0, stream>>>(pooled, wlin, blin, out);
}

// Round 8
// 290.945 us; speedup vs baseline: 1.7817x; 1.1987x over previous
//
#include <hip/hip_runtime.h>

#define N_NODES  80000
#define N_EDGES  1280000
#define N_GRAPHS 512
#define DIM      64
#define NCLS     10

#define ETILE    8192
#define NTILE    157      // ceil(N_EDGES / ETILE)
#define NCB      157      // ceil(N_NODES / 512) coarse buckets of 512 nodes
#define CBPAD    160

typedef short short8f __attribute__((ext_vector_type(8)));   // 8 bf16 (4 VGPRs)
typedef float float4f __attribute__((ext_vector_type(4)));   // 4 fp32 acc

static __device__ __forceinline__ unsigned short f2bf(float f) {
    unsigned u = __float_as_uint(f);
    unsigned r = (u + 0x7FFFu + ((u >> 16) & 1u)) >> 16;   // RNE
    return (unsigned short)r;
}
static __device__ __forceinline__ float bf_lo(unsigned v) { return __uint_as_float(v << 16); }
static __device__ __forceinline__ float bf_hi(unsigned v) { return __uint_as_float(v & 0xFFFF0000u); }

// ---------- Pass A: per-tile histogram over coarse buckets (no global atomics)
__global__ __launch_bounds__(256) void k_hist(const int* __restrict__ ei,
                                              int* __restrict__ hmat) {
    __shared__ int hist[NCB];
    int tile = blockIdx.x, t = threadIdx.x;
    for (int i = t; i < NCB; i += 256) hist[i] = 0;
    __syncthreads();
    int base = tile * ETILE;
    int end = base + ETILE; if (end > N_EDGES) end = N_EDGES;
    for (int i = base + t; i < end; i += 256)
        atomicAdd(&hist[ei[N_EDGES + i] >> 9], 1);
    __syncthreads();
    for (int i = t; i < NCB; i += 256) hmat[tile * CBPAD + i] = hist[i];
}

// ---------- Pass B1: per-bucket scan across tiles -> within-bucket offsets
__global__ __launch_bounds__(256) void k_scanT(const int* __restrict__ hmat,
        int* __restrict__ obase, int* __restrict__ btot) {
    __shared__ int sa[256], sb[256];
    int b = blockIdx.x, t = threadIdx.x;
    int v = (t < NTILE) ? hmat[t * CBPAD + b] : 0;
    sa[t] = v; __syncthreads();
    int* sp = sa; int* dp = sb;
    for (int off = 1; off < 256; off <<= 1) {
        dp[t] = sp[t] + ((t >= off) ? sp[t - off] : 0);
        __syncthreads();
        int* tmp = sp; sp = dp; dp = tmp;
    }
    int incl = sp[t];
    if (t < NTILE) obase[t * CBPAD + b] = incl - v;
    if (t == NTILE - 1) btot[b] = incl;
}

// ---------- Pass B2: scan bucket totals -> bucket bases
__global__ __launch_bounds__(256) void k_scanB(const int* __restrict__ btot,
        int* __restrict__ bucketbase, int* __restrict__ rowptr) {
    __shared__ int sa[256], sb[256];
    int t = threadIdx.x;
    int v = (t < NCB) ? btot[t] : 0;
    sa[t] = v; __syncthreads();
    int* sp = sa; int* dp = sb;
    for (int off = 1; off < 256; off <<= 1) {
        dp[t] = sp[t] + ((t >= off) ? sp[t - off] : 0);
        __syncthreads();
        int* tmp = sp; sp = dp; dp = tmp;
    }
    int incl = sp[t];
    if (t < NCB) bucketbase[t] = incl - v;
    if (t == 0) { bucketbase[NCB] = N_EDGES; rowptr[N_NODES] = N_EDGES; }
}

// ---------- Pass C: scatter into bucket-sorted ebuf (deterministic runs)
__global__ __launch_bounds__(256) void k_scatter(const int* __restrict__ ei,
        const int* __restrict__ obase, const int* __restrict__ bucketbase,
        int* __restrict__ ebuf) {
    __shared__ int cur[NCB];
    int tile = blockIdx.x, t = threadIdx.x;
    for (int i = t; i < NCB; i += 256)
        cur[i] = bucketbase[i] + obase[tile * CBPAD + i];
    __syncthreads();
    int base = tile * ETILE;
    int end = base + ETILE; if (end > N_EDGES) end = N_EDGES;
    for (int i = base + t; i < end; i += 256) {
        int s = ei[i], d = ei[N_EDGES + i];
        int p = atomicAdd(&cur[d >> 9], 1);
        ebuf[p] = s | ((d & 511) << 17);   // src:17 bits, local dst:9 bits
    }
}

// ---------- Pass D: per-bucket node-level CSR, all in LDS
__global__ __launch_bounds__(256) void k_csr(const int* __restrict__ ebuf,
        const int* __restrict__ bucketbase, int* __restrict__ rowptr,
        int* __restrict__ col) {
    __shared__ int cnt[512];
    __shared__ int sa[512], sb[512];
    __shared__ int cur[512];
    int b = blockIdx.x, t = threadIdx.x;
    int s = bucketbase[b], e = bucketbase[b + 1];
    cnt[t] = 0; cnt[t + 256] = 0;
    __syncthreads();
    for (int i = s + t; i < e; i += 256) atomicAdd(&cnt[ebuf[i] >> 17], 1);
    __syncthreads();
    sa[t] = cnt[t]; sa[t + 256] = cnt[t + 256];
    __syncthreads();
    int* sp = sa; int* dp = sb;
    for (int off = 1; off < 512; off <<= 1) {
        int i1 = t + 256;
        int v0 = sp[t]  + ((t  >= off) ? sp[t  - off] : 0);
        int v1 = sp[i1] + ((i1 >= off) ? sp[i1 - off] : 0);
        __syncthreads();
        dp[t] = v0; dp[i1] = v1;
        __syncthreads();
        int* tmp = sp; sp = dp; dp = tmp;
    }
    int node0 = b * 512;
    int base0 = s + sp[t] - cnt[t];
    int base1 = s + sp[t + 256] - cnt[t + 256];
    cur[t] = base0; cur[t + 256] = base1;
    if (node0 + t < N_NODES)       rowptr[node0 + t] = base0;
    if (node0 + t + 256 < N_NODES) rowptr[node0 + t + 256] = base1;
    __syncthreads();
    for (int i = s + t; i < e; i += 256) {
        int pk = ebuf[i];
        int p = atomicAdd(&cur[pk >> 17], 1);
        col[p] = pk & 0x1FFFF;
    }
}

// ---------- prep: cast x -> bf16 (blocks 0..4999) + pack W into MFMA B-frag
// order bf16 (blocks 5000..5095). wf[l][nt][ks][lane][j]: k=ks*32+quad*8+j,
// n=nt*16+(lane&15); W[k][n] = k<64 ? wrel[n][k] : wroot[n][k-64].
__global__ __launch_bounds__(256) void k_prep2(const float* __restrict__ x,
        const float* __restrict__ wr1, const float* __restrict__ wo1,
        const float* __restrict__ wr2, const float* __restrict__ wo2,
        const float* __restrict__ wr3, const float* __restrict__ wo3,
        unsigned short* __restrict__ xb, unsigned short* __restrict__ wf) {
    int bid = blockIdx.x, t = threadIdx.x;
    if (bid < 5000) {
        int i = bid * 256 + t;                  // N_NODES*16 float4s
        float4 v = ((const float4*)x)[i];
        ushort4 o;
        o.x = f2bf(v.x); o.y = f2bf(v.y); o.z = f2bf(v.z); o.w = f2bf(v.w);
        ((ushort4*)xb)[i] = o;
    } else {
        int idx = (bid - 5000) * 256 + t;       // < 3*8192
        int j = idx & 7, lane = (idx >> 3) & 63;
        int ks = (idx >> 9) & 3, nt = (idx >> 11) & 3, l = idx >> 13;
        int k = ks * 32 + ((lane >> 4) & 3) * 8 + j;
        int n = nt * 16 + (lane & 15);
        const float* wr = (l == 0) ? wr1 : (l == 1) ? wr2 : wr3;
        const float* wo = (l == 0) ? wo1 : (l == 1) ? wo2 : wo3;
        float val = (k < 64) ? wr[n * 64 + k] : wo[n * 64 + (k - 64)];
        wf[idx] = f2bf(val);
    }
}

// ---------- aggregation over bf16 rows: 2 nodes/wave, lane=dword, unroll 8
__global__ __launch_bounds__(256) void k_gather_bf(const unsigned short* __restrict__ Xbf,
        const int* __restrict__ rowptr, const int* __restrict__ col,
        unsigned short* __restrict__ agg) {
    const unsigned* Xu = (const unsigned*)Xbf;
    int t = threadIdx.x, w = t >> 6, lane = t & 63;
    int g = lane >> 5, c = lane & 31;
    int node = blockIdx.x * 8 + w * 2 + g;
    int start = rowptr[node], end = rowptr[node + 1];
    float alo = 0.f, ahi = 0.f;
    int e = start;
    for (; e + 8 <= end; e += 8) {
        int s0 = col[e],     s1 = col[e + 1], s2 = col[e + 2], s3 = col[e + 3];
        int s4 = col[e + 4], s5 = col[e + 5], s6 = col[e + 6], s7 = col[e + 7];
        unsigned v0 = Xu[(size_t)s0 * 32 + c];
        unsigned v1 = Xu[(size_t)s1 * 32 + c];
        unsigned v2 = Xu[(size_t)s2 * 32 + c];
        unsigned v3 = Xu[(size_t)s3 * 32 + c];
        unsigned v4 = Xu[(size_t)s4 * 32 + c];
        unsigned v5 = Xu[(size_t)s5 * 32 + c];
        unsigned v6 = Xu[(size_t)s6 * 32 + c];
        unsigned v7 = Xu[(size_t)s7 * 32 + c];
        alo += ((bf_lo(v0) + bf_lo(v1)) + (bf_lo(v2) + bf_lo(v3)))
             + ((bf_lo(v4) + bf_lo(v5)) + (bf_lo(v6) + bf_lo(v7)));
        ahi += ((bf_hi(v0) + bf_hi(v1)) + (bf_hi(v2) + bf_hi(v3)))
             + ((bf_hi(v4) + bf_hi(v5)) + (bf_hi(v6) + bf_hi(v7)));
    }
    for (; e < end; ++e) {
        unsigned v = Xu[(size_t)col[e] * 32 + c];
        alo += bf_lo(v); ahi += bf_hi(v);
    }
    unsigned o = (unsigned)f2bf(alo) | ((unsigned)f2bf(ahi) << 16);
    ((unsigned*)agg)[(size_t)node * 32 + c] = o;
}

// ---------- MFMA linear: out = act([agg|x] @ W + b), bf16 in/out, no LDS
// wave = 16 nodes x 64 outch; A direct from global (A[m=lane&15][k=quad*8+j]);
// B pre-packed frags; D: col=lane&15, row=quad*4+reg (m89-verified).
__global__ __launch_bounds__(256) void k_linear_mfma(
        const unsigned short* __restrict__ aggb, const unsigned short* __restrict__ xb,
        const unsigned short* __restrict__ wf, const float* __restrict__ bias,
        unsigned short* __restrict__ out, int relu) {
    int t = threadIdx.x, w = t >> 6, lane = t & 63;
    int quad = lane >> 4, l15 = lane & 15;
    int mbase = blockIdx.x * 64 + w * 16;
    size_t arow = (size_t)(mbase + l15) * 64;
    short8f a0 = *(const short8f*)(aggb + arow + quad * 8);
    short8f a1 = *(const short8f*)(aggb + arow + 32 + quad * 8);
    short8f a2 = *(const short8f*)(xb   + arow + quad * 8);
    short8f a3 = *(const short8f*)(xb   + arow + 32 + quad * 8);
    int orow = mbase + quad * 4;
#pragma unroll
    for (int nt = 0; nt < 4; ++nt) {
        const unsigned short* wp = wf + ((size_t)(nt * 4) * 64 + lane) * 8;
        short8f b0 = *(const short8f*)(wp);
        short8f b1 = *(const short8f*)(wp + 64 * 8);
        short8f b2 = *(const short8f*)(wp + 128 * 8);
        short8f b3 = *(const short8f*)(wp + 192 * 8);
        float4f acc = {0.f, 0.f, 0.f, 0.f};
        acc = __builtin_amdgcn_mfma_f32_16x16x32_bf16(a0, b0, acc, 0, 0, 0);
        acc = __builtin_amdgcn_mfma_f32_16x16x32_bf16(a1, b1, acc, 0, 0, 0);
        acc = __builtin_amdgcn_mfma_f32_16x16x32_bf16(a2, b2, acc, 0, 0, 0);
        acc = __builtin_amdgcn_mfma_f32_16x16x32_bf16(a3, b3, acc, 0, 0, 0);
        float bi = bias[nt * 16 + l15];
#pragma unroll
        for (int r = 0; r < 4; ++r) {
            float v = acc[r] + bi;
            if (relu) v = fmaxf(v, 0.f);
            out[(size_t)(orow + r) * 64 + nt * 16 + l15] = f2bf(v);
        }
    }
}

// ---------- fused mean pool + linear head ----------
static __device__ __forceinline__ int lowerb(const int* a, int n, int key) {
    int lo = 0, hi = n;
    while (lo < hi) { int mid = (lo + hi) >> 1; if (a[mid] < key) lo = mid + 1; else hi = mid; }
    return lo;
}

__global__ __launch_bounds__(256) void k_poolhead(const unsigned short* __restrict__ h,
        const int* __restrict__ batch, const float* __restrict__ wlin,
        const float* __restrict__ blin, float* __restrict__ out) {
    __shared__ float sp[8][64];
    int gph = blockIdx.x;
    int t = threadIdx.x, sub = t >> 5, c = t & 31;
    int start = lowerb(batch, N_NODES, gph);
    int end   = lowerb(batch, N_NODES, gph + 1);
    const unsigned* hu = (const unsigned*)h;
    float alo = 0.f, ahi = 0.f;
    for (int i = start + sub; i < end; i += 8) {
        unsigned v = hu[(size_t)i * 32 + c];
        alo += bf_lo(v); ahi += bf_hi(v);
    }
    sp[sub][2 * c] = alo; sp[sub][2 * c + 1] = ahi;
    __syncthreads();
    if (t < 64) {          // wave 0 only
        float v = 0.f;
#pragma unroll
        for (int s = 0; s < 8; ++s) v += sp[s][t];
        int cnt = end - start;
        v /= (float)((cnt > 0) ? cnt : 1);
        float myout = 0.f;
        for (int cls = 0; cls < NCLS; ++cls) {
            float vv = v * wlin[cls * 64 + t];
            for (int off = 32; off > 0; off >>= 1) vv += __shfl_xor(vv, off);
            if (t == cls) myout = vv + blin[cls];
        }
        if (t < NCLS) out[gph * NCLS + t] = myout;
    }
}

extern "C" void kernel_launch(void* const* d_in, const int* in_sizes, int n_in,
                              void* d_out, int out_size, void* d_ws, size_t ws_size,
                              hipStream_t stream) {
    const float* x     = (const float*)d_in[0];
    const int*   ei    = (const int*)d_in[1];
    const int*   batch = (const int*)d_in[2];
    const float* wr1 = (const float*)d_in[3];
    const float* b1  = (const float*)d_in[4];
    const float* wo1 = (const float*)d_in[5];
    const float* wr2 = (const float*)d_in[6];
    const float* b2  = (const float*)d_in[7];
    const float* wo2 = (const float*)d_in[8];
    const float* wr3 = (const float*)d_in[9];
    const float* b3  = (const float*)d_in[10];
    const float* wo3 = (const float*)d_in[11];
    const float* wlin = (const float*)d_in[12];
    const float* blin = (const float*)d_in[13];
    float* out = (float*)d_out;

    char* p = (char*)d_ws;
    auto alloc = [&](size_t bytes) { char* r = p; p += (bytes + 255) & ~(size_t)255; return r; };
    int*   rowptr  = (int*)alloc((N_NODES + 1) * sizeof(int));
    int*   hmat    = (int*)alloc((size_t)NTILE * CBPAD * sizeof(int));
    int*   obase   = (int*)alloc((size_t)NTILE * CBPAD * sizeof(int));
    int*   btot    = (int*)alloc(CBPAD * sizeof(int));
    int*   bucketbase = (int*)alloc((NCB + 1) * sizeof(int));
    int*   ebuf    = (int*)alloc((size_t)N_EDGES * sizeof(int));
    int*   col     = (int*)alloc((size_t)N_EDGES * sizeof(int));
    unsigned short* wf  = (unsigned short*)alloc(3 * 8192 * sizeof(unsigned short));
    unsigned short* xbf = (unsigned short*)alloc((size_t)N_NODES * 64 * 2);
    unsigned short* agg = (unsigned short*)alloc((size_t)N_NODES * 64 * 2);
    unsigned short* hA  = (unsigned short*)alloc((size_t)N_NODES * 64 * 2);
    unsigned short* hB  = (unsigned short*)alloc((size_t)N_NODES * 64 * 2);

    // CSR build: deterministic two-level counting sort, zero global atomics
    k_hist   <<<NTILE, 256, 0, stream>>>(ei, hmat);
    k_scanT  <<<NCB,   256, 0, stream>>>(hmat, obase, btot);
    k_scanB  <<<1,     256, 0, stream>>>(btot, bucketbase, rowptr);
    k_scatter<<<NTILE, 256, 0, stream>>>(ei, obase, bucketbase, ebuf);
    k_csr    <<<NCB,   256, 0, stream>>>(ebuf, bucketbase, rowptr, col);
    k_prep2  <<<5096,  256, 0, stream>>>(x, wr1, wo1, wr2, wo2, wr3, wo3, xbf, wf);

    // layer 1
    k_gather_bf  <<<N_NODES / 8,  256, 0, stream>>>(xbf, rowptr, col, agg);
    k_linear_mfma<<<N_NODES / 64, 256, 0, stream>>>(agg, xbf, wf,         b1, hA, 1);
    // layer 2
    k_gather_bf  <<<N_NODES / 8,  256, 0, stream>>>(hA, rowptr, col, agg);
    k_linear_mfma<<<N_NODES / 64, 256, 0, stream>>>(agg, hA, wf + 8192,   b2, hB, 1);
    // layer 3
    k_gather_bf  <<<N_NODES / 8,  256, 0, stream>>>(hB, rowptr, col, agg);
    k_linear_mfma<<<N_NODES / 64, 256, 0, stream>>>(agg, hB, wf + 16384,  b3, hA, 0);

    // pool + head (fused)
    k_poolhead<<<N_GRAPHS, 256, 0, stream>>>(hA, batch, wlin, blin, out);
}